// Round 13
// baseline (127.308 us; speedup 1.0000x reference)
//
#include <hip/hip_runtime.h>

// Problem constants:
//   B=16, P1=25, P2=24 -> S=600 tokens; E=(8,8,16)=1024; heads (2,2,4)=16, head_dim 64
#define S   600
#define NB  16
#define NH  16
#define HD  64
// Q pre-scale: (head_dim)^-0.5 * log2(e): scores in log2 domain -> softmax uses exp2.
#define QSCALE 0.18033688011112042f

#define LDT 20   // TCL intermediate row stride (floats)

typedef _Float16 f16x8 __attribute__((ext_vector_type(8)));
typedef float f32x4 __attribute__((ext_vector_type(4)));

// ---------------------------------------------------------------------------
// Kernel A: TCL for q,k,v — wave-per-token, barrier-free (unchanged).
// ---------------------------------------------------------------------------
__global__ __launch_bounds__(256) void tcl_qkv_kernel(
    const float* __restrict__ x,
    const float* __restrict__ qw0, const float* __restrict__ qw1,
    const float* __restrict__ qw2, const float* __restrict__ qb,
    const float* __restrict__ kw0, const float* __restrict__ kw1,
    const float* __restrict__ kw2, const float* __restrict__ kb,
    const float* __restrict__ vw0, const float* __restrict__ vw1,
    const float* __restrict__ vw2, const float* __restrict__ vb,
    _Float16* __restrict__ Qh, _Float16* __restrict__ Kh,
    _Float16* __restrict__ Vh)
{
  __shared__ __align__(16) float t1s[4][64 * LDT];
  __shared__ __align__(16) float t2s[4][64 * LDT];

  const int tid = threadIdx.x;
  const int wv = tid >> 6, lane = tid & 63;
  const int tok = blockIdx.x * 4 + wv;
  const int b = tok / S, t = tok - b * S;
  const int q = lane >> 3, zp = lane & 7;
  float* __restrict__ t1 = t1s[wv];
  float* __restrict__ t2 = t2s[wv];

  float2 xc[8];
  #pragma unroll
  for (int xx = 0; xx < 8; ++xx)
    xc[xx] = *(const float2*)&x[(size_t)tok * 1024 + xx * 128 + q * 16 + zp * 2];

  const int xs = lane >> 4;
  const int h1 = (lane >> 3) & 1;
  const int cc = lane & 7;
  const int ys = cc >> 1, h2 = cc & 1;

  const float* W0[3] = {qw0, kw0, vw0};
  const float* W1[3] = {qw1, kw1, vw1};
  const float* W2[3] = {qw2, kw2, vw2};
  const float* BB[3] = {qb, kb, vb};
  _Float16* OUT[3] = {Qh, Kh, Vh};

  #pragma unroll
  for (int p = 0; p < 3; ++p) {
    const float* __restrict__ w0 = W0[p];
    const float* __restrict__ w1 = W1[p];
    const float* __restrict__ w2 = W2[p];
    const float* __restrict__ bb = BB[p];
    _Float16* __restrict__ op = OUT[p];

    #pragma unroll
    for (int a = 0; a < 8; ++a) {
      float2 r = make_float2(0.f, 0.f);
      #pragma unroll
      for (int xx = 0; xx < 8; ++xx) {
        const float w = w0[a * 8 + xx];
        r.x = fmaf(w, xc[xx].x, r.x);
        r.y = fmaf(w, xc[xx].y, r.y);
      }
      *(float2*)&t1[(a * 8 + q) * LDT + zp * 2] = r;
    }
    __builtin_amdgcn_wave_barrier();

    float2 t1r[8];
    #pragma unroll
    for (int y = 0; y < 8; ++y)
      t1r[y] = *(float2*)&t1[(q * 8 + y) * LDT + zp * 2];
    #pragma unroll
    for (int c = 0; c < 8; ++c) {
      float2 r = make_float2(0.f, 0.f);
      #pragma unroll
      for (int y = 0; y < 8; ++y) {
        const float w = w1[c * 8 + y];
        r.x = fmaf(w, t1r[y].x, r.x);
        r.y = fmaf(w, t1r[y].y, r.y);
      }
      *(float2*)&t2[(q * 8 + c) * LDT + zp * 2] = r;
    }
    __builtin_amdgcn_wave_barrier();

    float t2r[16];
    #pragma unroll
    for (int k = 0; k < 4; ++k)
      *(float4*)&t2r[k * 4] = *(float4*)&t2[lane * LDT + k * 4];
    float bias[16];
    #pragma unroll
    for (int k = 0; k < 4; ++k)
      *(float4*)&bias[k * 4] = *(const float4*)&bb[lane * 16 + k * 4];
    float o[16];
    #pragma unroll
    for (int d = 0; d < 16; ++d) {
      float acc = 0.f;
      #pragma unroll
      for (int j = 0; j < 16; ++j)
        acc = fmaf(w2[d * 16 + j], t2r[j], acc);
      o[d] = acc + bias[d];
    }
    const float sc = (p == 0) ? QSCALE : 1.0f;
    #pragma unroll
    for (int h3 = 0; h3 < 4; ++h3) {
      union { _Float16 hh[4]; uint2 u; } pk;
      #pragma unroll
      for (int z = 0; z < 4; ++z)
        pk.hh[z] = (_Float16)(o[4 * z + h3] * sc);
      const int head = h1 * 8 + h2 * 4 + h3;
      *(uint2*)&op[((size_t)((b * NH + head) * S + t)) * HD + xs * 16 + ys * 4]
          = pk.u;
    }
    __builtin_amdgcn_wave_barrier();
  }
}

// ---------------------------------------------------------------------------
// Kernel A2: V [b,h,600,64] f16 -> Vt [b,h,64,600] f16 (unchanged).
// ---------------------------------------------------------------------------
__global__ __launch_bounds__(256) void vtrans_kernel(
    const _Float16* __restrict__ Vh, _Float16* __restrict__ Vt)
{
  __shared__ __align__(16) _Float16 tile[64 * 64];
  const int tid = threadIdx.x;
  const int tt = blockIdx.x, h = blockIdx.y, b = blockIdx.z;
  const size_t rbase = (size_t)(b * NH + h) * S * HD;
  const size_t wbase = (size_t)(b * NH + h) * HD * S;
  const int t0 = tt * 64;

  #pragma unroll
  for (int hp = 0; hp < 2; ++hp) {
    const int u = hp * 256 + tid;
    const int r = u >> 3, ch = u & 7;
    f16x8 v = {0, 0, 0, 0, 0, 0, 0, 0};
    if (t0 + r < S) v = *(const f16x8*)&Vh[rbase + (size_t)(t0 + r) * HD + ch * 8];
    *(f16x8*)&tile[r * 64 + ((ch ^ ((r ^ (r >> 3)) & 7)) * 8)] = v;
  }
  __syncthreads();
  #pragma unroll
  for (int hp = 0; hp < 2; ++hp) {
    const int w = hp * 256 + tid;
    const int d = w >> 3, tc = w & 7;
    if (t0 + tc * 8 + 8 <= S) {
      const int cd = d >> 3;
      union { _Float16 hh[8]; f16x8 v; } g;
      #pragma unroll
      for (int e = 0; e < 8; ++e) {
        const int r = tc * 8 + e;
        g.hh[e] = tile[r * 64 + ((cd ^ ((r ^ (r >> 3)) & 7)) * 8) + (d & 7)];
      }
      *(f16x8*)&Vt[wbase + (size_t)d * S + t0 + tc * 8] = g.v;
    }
  }
}

// ---------------------------------------------------------------------------
// Kernel B: MFMA flash attention — KVBLK=32 for occupancy. LDS 20 KB ->
// 8 blocks/CU (32 waves, vs 16 at R12's 40 KB): doubles TLP to hide the
// per-wave QK->softmax->PV chain. 19 K-tiles (18 full + 24-key tail).
// Staging still global_load_lds (w=16), dbuf, one barrier/tile, sources
// pre-swizzled. Tail garbage (K rows >=600 spill, V chunk 3) is finite f16
// in-workspace data; scores masked -> P=0 -> contributes exact zeros.
// ---------------------------------------------------------------------------
__device__ __forceinline__ void gload16(const _Float16* g, _Float16* l) {
  __builtin_amdgcn_global_load_lds(
      (const __attribute__((address_space(1))) unsigned int*)g,
      (__attribute__((address_space(3))) unsigned int*)l, 16, 0, 0);
}

template<bool TAIL>
__device__ __forceinline__ void attn_step(
    const _Float16* __restrict__ Ks, const _Float16* __restrict__ Vs,
    _Float16* __restrict__ Pw,
    const f16x8 qf0, const f16x8 qf1,
    f32x4 (&po)[4], float& mrow, float& lrow,
    const int lr, const int lg)
{
  // --- QK^T: 32 keys x 16 q, K-dim 64 (2 chunks) ---
  f32x4 accs[2] = {{0.f,0.f,0.f,0.f},{0.f,0.f,0.f,0.f}};
  __builtin_amdgcn_s_setprio(1);
  #pragma unroll
  for (int c = 0; c < 2; ++c) {
    const f16x8 qf = c ? qf1 : qf0;
    #pragma unroll
    for (int mt = 0; mt < 2; ++mt) {
      const int krow = mt * 16 + lr;
      const f16x8 kf = *(const f16x8*)
          &Ks[krow * 64 + (((4 * c + lg) ^ (krow & 7)) * 8)];
      accs[mt] = __builtin_amdgcn_mfma_f32_16x16x32_f16(kf, qf, accs[mt], 0, 0, 0);
    }
  }
  __builtin_amdgcn_s_setprio(0);
  // --- online softmax (lane owns q-row lr; keys mt*16+4*lg+r) ---
  float sv[2][4];
  #pragma unroll
  for (int mt = 0; mt < 2; ++mt)
    #pragma unroll
    for (int r = 0; r < 4; ++r) {
      float s = accs[mt][r];
      if (TAIL && mt == 1) s = (lg < 2) ? s : -1e30f;  // keys >= 600 dead
      sv[mt][r] = s;
    }
  float tmax;
  {
    const float a = fmaxf(fmaxf(sv[0][0], sv[0][1]), fmaxf(sv[0][2], sv[0][3]));
    const float b = fmaxf(fmaxf(sv[1][0], sv[1][1]), fmaxf(sv[1][2], sv[1][3]));
    tmax = fmaxf(a, b);
  }
  tmax = fmaxf(tmax, __shfl_xor(tmax, 16));
  tmax = fmaxf(tmax, __shfl_xor(tmax, 32));
  if (!__all(tmax - mrow <= 11.0f)) {   // defer-max (P <= 2^11, f16-safe)
    const float mn = fmaxf(mrow, tmax);
    const float corr = __builtin_amdgcn_exp2f(mrow - mn);
    lrow *= corr;
    #pragma unroll
    for (int dt = 0; dt < 4; ++dt) {
      po[dt][0] *= corr; po[dt][1] *= corr;
      po[dt][2] *= corr; po[dt][3] *= corr;
    }
    mrow = mn;
  }
  float rs = 0.f;
  #pragma unroll
  for (int mt = 0; mt < 2; ++mt) {
    const float e0 = __builtin_amdgcn_exp2f(sv[mt][0] - mrow);
    const float e1 = __builtin_amdgcn_exp2f(sv[mt][1] - mrow);
    const float e2 = __builtin_amdgcn_exp2f(sv[mt][2] - mrow);
    const float e3 = __builtin_amdgcn_exp2f(sv[mt][3] - mrow);
    rs += (e0 + e1) + (e2 + e3);
    union { _Float16 hh[4]; unsigned long long u; } pk;
    pk.hh[0] = (_Float16)e0; pk.hh[1] = (_Float16)e1;
    pk.hh[2] = (_Float16)e2; pk.hh[3] = (_Float16)e3;
    // key j = mt*16+4lg+r -> chunk 2mt+(lg>>1), in-chunk off (lg&1)*4+r
    const int slot = (2 * mt + (lg >> 1)) ^ (lr & 3);
    *(unsigned long long*)&Pw[lr * 32 + slot * 8 + (lg & 1) * 4] = pk.u;
  }
  rs += __shfl_xor(rs, 16);
  rs += __shfl_xor(rs, 32);
  lrow += rs;
  __builtin_amdgcn_wave_barrier();   // fence: P writes before P reads (same wave)
  // --- O^T += V^T * P^T (K-dim 32: single chunk) ---
  __builtin_amdgcn_s_setprio(1);
  const f16x8 pf = *(const f16x8*)&Pw[lr * 32 + ((lg ^ (lr & 3)) * 8)];
  #pragma unroll
  for (int dt = 0; dt < 4; ++dt) {
    const int drow = dt * 16 + lr;
    const f16x8 vf = *(const f16x8*)
        &Vs[drow * 32 + (((lg) ^ (drow & 3)) * 8)];
    po[dt] = __builtin_amdgcn_mfma_f32_16x16x32_f16(vf, pf, po[dt], 0, 0, 0);
  }
  __builtin_amdgcn_s_setprio(0);
}

__global__ __launch_bounds__(256) void attn_mfma_kernel(
    const _Float16* __restrict__ Qh, const _Float16* __restrict__ Kh,
    const _Float16* __restrict__ Vt, float* __restrict__ Og)
{
  __shared__ __align__(16) union {
    struct {
      _Float16 K[2][32 * 64];   // dbuf, swizzled [key][d]   8 KB
      _Float16 V[2][64 * 32];   // dbuf, swizzled [d][key]   8 KB
      _Float16 P[4][16 * 32];   // per-wave P relay           4 KB
    } m;                        // 20480 B -> 8 blocks/CU
    float ot[4][64 * 17];       // epilogue staging (17408 B)
  } sm;

  const int tid = threadIdx.x;
  const int lane = tid & 63;
  const int wv = tid >> 6;
  // XCD-aware decode: all 10 q-tiles of a (b,h) co-locate on one XCD.
  const int id = blockIdx.x;
  const int idx = id >> 3;
  const int bh = (id & 7) * 32 + idx / 10;
  const int qt = idx - (idx / 10) * 10;
  const size_t base  = (size_t)bh * S * HD;
  const size_t vbase = (size_t)bh * HD * S;
  const int lr = lane & 15;
  const int lg = lane >> 4;

  const int qrow_l = qt * 64 + wv * 16 + lr;
  const int qrow = (qrow_l < S) ? qrow_l : (S - 1);
  const f16x8 qf0 = *(const f16x8*)&Qh[base + (size_t)qrow * HD + lg * 8];
  const f16x8 qf1 = *(const f16x8*)&Qh[base + (size_t)qrow * HD + 32 + lg * 8];

  f32x4 po[4] = {{0.f,0.f,0.f,0.f},{0.f,0.f,0.f,0.f},
                 {0.f,0.f,0.f,0.f},{0.f,0.f,0.f,0.f}};
  float mrow = -1e30f, lrow = 0.f;

  // K staging: wave wv owns rows wv*8..+8 (chunks of 8 f16, 8 per row).
  //   lane l=(sr,ss): LDS slot (row sr, chunk ss) <- global chunk ss^sr.
  // V staging: wave wv owns d-rows wv*16..+16 (4 chunks of 8 f16 per row).
  //   lane l=(vr,vc): LDS slot (row vr, chunk vc) <- global chunk vc^(vr&3).
  const int sr = lane >> 3, ss = lane & 7;
  const int vr = lane >> 2, vc = lane & 3;
  const _Float16* kgp = Kh + base + (size_t)(wv * 8 + sr) * HD + ((ss ^ sr) * 8);
  const _Float16* vgp = Vt + vbase + (size_t)(wv * 16 + vr) * S
                      + ((vc ^ (vr & 3)) * 8);

  auto gload_tile = [&](int kt, int b) {
    const int kb = kt * 32;
    gload16(kgp + (size_t)kb * HD, &sm.m.K[b][wv * 512]);
    gload16(vgp + kb, &sm.m.V[b][wv * 512]);
  };

  gload_tile(0, 0);
  #pragma unroll 2
  for (int kt = 0; kt < 18; ++kt) {
    const int b = kt & 1;
    __syncthreads();              // drains tile-kt gloads; orders buf^1 WAR
    gload_tile(kt + 1, b ^ 1);    // streams during attn_step below
    attn_step<false>(&sm.m.K[b][0], &sm.m.V[b][0], &sm.m.P[wv][0],
                     qf0, qf1, po, mrow, lrow, lr, lg);
  }
  __syncthreads();                // tile-18 gloads drained (buf 0)
  attn_step<true>(&sm.m.K[0][0], &sm.m.V[0][0], &sm.m.P[wv][0],
                  qf0, qf1, po, mrow, lrow, lr, lg);
  __syncthreads();   // main-loop LDS fully consumed before epilogue reuse

  const float invl = 1.0f / lrow;
  #pragma unroll
  for (int dt = 0; dt < 4; ++dt)
    #pragma unroll
    for (int r = 0; r < 4; ++r)
      sm.ot[wv][(dt * 16 + 4 * lg + r) * 17 + lr] = po[dt][r] * invl;
  __builtin_amdgcn_wave_barrier();   // fence: ot writes before ot reads (same wave)
  #pragma unroll
  for (int ps = 0; ps < 4; ++ps) {
    const int qr = ps * 4 + lg;
    const int gq = qt * 64 + wv * 16 + qr;
    if (gq < S) {
      const int d0 = lr * 4;
      float4 o4;
      o4.x = sm.ot[wv][(d0 + 0) * 17 + qr];
      o4.y = sm.ot[wv][(d0 + 1) * 17 + qr];
      o4.z = sm.ot[wv][(d0 + 2) * 17 + qr];
      o4.w = sm.ot[wv][(d0 + 3) * 17 + qr];
      *(float4*)&Og[base + (size_t)gq * HD + d0] = o4;
    }
  }
}

// ---------------------------------------------------------------------------
// Kernel C: output TCL — wave-per-token, barrier-free (unchanged).
// ---------------------------------------------------------------------------
__global__ __launch_bounds__(256) void tcl_out_kernel(
    const float* __restrict__ Og,
    const float* __restrict__ ow0, const float* __restrict__ ow1,
    const float* __restrict__ ow2, const float* __restrict__ ob,
    float* __restrict__ out)
{
  __shared__ __align__(16) float t1s[4][64 * LDT];
  __shared__ __align__(16) float t2s[4][64 * LDT];

  const int tid = threadIdx.x;
  const int wv = tid >> 6, lane = tid & 63;
  const int tok = blockIdx.x * 4 + wv;
  const int b = tok / S, t = tok - b * S;
  const int q = lane >> 3, zp = lane & 7;
  float* __restrict__ t1 = t1s[wv];
  float* __restrict__ t2 = t2s[wv];

  float2 xc[8];
  {
    const int h2g = q & 1, yg = q >> 1;
    const int h3g = 2 * (zp & 1), zg = zp >> 1;
    #pragma unroll
    for (int xx = 0; xx < 8; ++xx) {
      const int headb = (xx & 1) * 8 + h2g * 4 + h3g;
      const size_t off = ((size_t)((b * NH + headb) * S + t)) * HD
                       + (xx >> 1) * 16 + yg * 4 + zg;
      xc[xx].x = Og[off];
      xc[xx].y = Og[off + (size_t)S * HD];
    }
  }

  #pragma unroll
  for (int a = 0; a < 8; ++a) {
    float2 r = make_float2(0.f, 0.f);
    #pragma unroll
    for (int xx = 0; xx < 8; ++xx) {
      const float w = ow0[a * 8 + xx];
      r.x = fmaf(w, xc[xx].x, r.x);
      r.y = fmaf(w, xc[xx].y, r.y);
    }
    *(float2*)&t1[(a * 8 + q) * LDT + zp * 2] = r;
  }
  __builtin_amdgcn_wave_barrier();

  float2 t1r[8];
  #pragma unroll
  for (int y = 0; y < 8; ++y)
    t1r[y] = *(float2*)&t1[(q * 8 + y) * LDT + zp * 2];
  #pragma unroll
  for (int c = 0; c < 8; ++c) {
    float2 r = make_float2(0.f, 0.f);
    #pragma unroll
    for (int y = 0; y < 8; ++y) {
      const float w = ow1[c * 8 + y];
      r.x = fmaf(w, t1r[y].x, r.x);
      r.y = fmaf(w, t1r[y].y, r.y);
    }
    *(float2*)&t2[(q * 8 + c) * LDT + zp * 2] = r;
  }
  __builtin_amdgcn_wave_barrier();

  float t2r[16];
  #pragma unroll
  for (int k = 0; k < 4; ++k)
    *(float4*)&t2r[k * 4] = *(float4*)&t2[lane * LDT + k * 4];
  float bias[16];
  #pragma unroll
  for (int k = 0; k < 4; ++k)
    *(float4*)&bias[k * 4] = *(const float4*)&ob[lane * 16 + k * 4];
  float o[16];
  #pragma unroll
  for (int d = 0; d < 16; ++d) {
    float acc = 0.f;
    #pragma unroll
    for (int j = 0; j < 16; ++j)
      acc = fmaf(ow2[d * 16 + j], t2r[j], acc);
    o[d] = acc + bias[d];
  }
  #pragma unroll
  for (int k = 0; k < 4; ++k) {
    const float4 res = make_float4(o[4 * k], o[4 * k + 1],
                                   o[4 * k + 2], o[4 * k + 3]);
    *(float4*)&out[(size_t)tok * 1024 + lane * 16 + k * 4] = res;
  }
}

// ---------------------------------------------------------------------------
extern "C" void kernel_launch(void* const* d_in, const int* in_sizes, int n_in,
                              void* d_out, int out_size, void* d_ws, size_t ws_size,
                              hipStream_t stream) {
  const float* x   = (const float*)d_in[0];
  const float* qw0 = (const float*)d_in[1];
  const float* qw1 = (const float*)d_in[2];
  const float* qw2 = (const float*)d_in[3];
  const float* qb  = (const float*)d_in[4];
  const float* kw0 = (const float*)d_in[5];
  const float* kw1 = (const float*)d_in[6];
  const float* kw2 = (const float*)d_in[7];
  const float* kb  = (const float*)d_in[8];
  const float* vw0 = (const float*)d_in[9];
  const float* vw1 = (const float*)d_in[10];
  const float* vw2 = (const float*)d_in[11];
  const float* vb  = (const float*)d_in[12];
  const float* ow0 = (const float*)d_in[13];
  const float* ow1 = (const float*)d_in[14];
  const float* ow2 = (const float*)d_in[15];
  const float* ob  = (const float*)d_in[16];

  const size_t N = (size_t)NB * NH * S * HD;  // 9,830,400 elems per logical buffer
  _Float16* Qh  = (_Float16*)d_ws;
  _Float16* Kh  = Qh + N;
  _Float16* Vth = Kh + N;
  _Float16* Vh  = Vth + N;            // row-major V temp, later reused as O
  float*    O   = (float*)Vh;
  // total ws use: 3*N*2 + N*4 = 98.3 MB

  tcl_qkv_kernel<<<dim3(NB * S / 4), 256, 0, stream>>>(
      x, qw0, qw1, qw2, qb, kw0, kw1, kw2, kb, vw0, vw1, vw2, vb, Qh, Kh, Vh);
  vtrans_kernel<<<dim3(10, NH, NB), 256, 0, stream>>>(Vh, Vth);
  attn_mfma_kernel<<<dim3(2560), 256, 0, stream>>>(Qh, Kh, Vth, O);
  tcl_out_kernel<<<dim3(NB * S / 4), 256, 0, stream>>>(O, ow0, ow1, ow2, ob,
                                                       (float*)d_out);
}

// Round 14
// 119.167 us; speedup vs baseline: 1.0683x; 1.0683x over previous
//
#include <hip/hip_runtime.h>

// Problem constants:
//   B=16, P1=25, P2=24 -> S=600 tokens; E=(8,8,16)=1024; heads (2,2,4)=16, head_dim 64
#define S   600
#define NB  16
#define NH  16
#define HD  64
// Q pre-scale: (head_dim)^-0.5 * log2(e): scores in log2 domain -> softmax uses exp2.
#define QSCALE 0.18033688011112042f

#define LDT 20   // TCL intermediate row stride (floats)

typedef _Float16 f16x8 __attribute__((ext_vector_type(8)));
typedef float f32x4 __attribute__((ext_vector_type(4)));
typedef float f32x16 __attribute__((ext_vector_type(16)));

// ---------------------------------------------------------------------------
// Kernel A: TCL for q,k,v — wave-per-token, barrier-free (unchanged).
// ---------------------------------------------------------------------------
__global__ __launch_bounds__(256) void tcl_qkv_kernel(
    const float* __restrict__ x,
    const float* __restrict__ qw0, const float* __restrict__ qw1,
    const float* __restrict__ qw2, const float* __restrict__ qb,
    const float* __restrict__ kw0, const float* __restrict__ kw1,
    const float* __restrict__ kw2, const float* __restrict__ kb,
    const float* __restrict__ vw0, const float* __restrict__ vw1,
    const float* __restrict__ vw2, const float* __restrict__ vb,
    _Float16* __restrict__ Qh, _Float16* __restrict__ Kh,
    _Float16* __restrict__ Vh)
{
  __shared__ __align__(16) float t1s[4][64 * LDT];
  __shared__ __align__(16) float t2s[4][64 * LDT];

  const int tid = threadIdx.x;
  const int wv = tid >> 6, lane = tid & 63;
  const int tok = blockIdx.x * 4 + wv;
  const int b = tok / S, t = tok - b * S;
  const int q = lane >> 3, zp = lane & 7;
  float* __restrict__ t1 = t1s[wv];
  float* __restrict__ t2 = t2s[wv];

  float2 xc[8];
  #pragma unroll
  for (int xx = 0; xx < 8; ++xx)
    xc[xx] = *(const float2*)&x[(size_t)tok * 1024 + xx * 128 + q * 16 + zp * 2];

  const int xs = lane >> 4;
  const int h1 = (lane >> 3) & 1;
  const int cc = lane & 7;
  const int ys = cc >> 1, h2 = cc & 1;

  const float* W0[3] = {qw0, kw0, vw0};
  const float* W1[3] = {qw1, kw1, vw1};
  const float* W2[3] = {qw2, kw2, vw2};
  const float* BB[3] = {qb, kb, vb};
  _Float16* OUT[3] = {Qh, Kh, Vh};

  #pragma unroll
  for (int p = 0; p < 3; ++p) {
    const float* __restrict__ w0 = W0[p];
    const float* __restrict__ w1 = W1[p];
    const float* __restrict__ w2 = W2[p];
    const float* __restrict__ bb = BB[p];
    _Float16* __restrict__ op = OUT[p];

    #pragma unroll
    for (int a = 0; a < 8; ++a) {
      float2 r = make_float2(0.f, 0.f);
      #pragma unroll
      for (int xx = 0; xx < 8; ++xx) {
        const float w = w0[a * 8 + xx];
        r.x = fmaf(w, xc[xx].x, r.x);
        r.y = fmaf(w, xc[xx].y, r.y);
      }
      *(float2*)&t1[(a * 8 + q) * LDT + zp * 2] = r;
    }
    __builtin_amdgcn_wave_barrier();

    float2 t1r[8];
    #pragma unroll
    for (int y = 0; y < 8; ++y)
      t1r[y] = *(float2*)&t1[(q * 8 + y) * LDT + zp * 2];
    #pragma unroll
    for (int c = 0; c < 8; ++c) {
      float2 r = make_float2(0.f, 0.f);
      #pragma unroll
      for (int y = 0; y < 8; ++y) {
        const float w = w1[c * 8 + y];
        r.x = fmaf(w, t1r[y].x, r.x);
        r.y = fmaf(w, t1r[y].y, r.y);
      }
      *(float2*)&t2[(q * 8 + c) * LDT + zp * 2] = r;
    }
    __builtin_amdgcn_wave_barrier();

    float t2r[16];
    #pragma unroll
    for (int k = 0; k < 4; ++k)
      *(float4*)&t2r[k * 4] = *(float4*)&t2[lane * LDT + k * 4];
    float bias[16];
    #pragma unroll
    for (int k = 0; k < 4; ++k)
      *(float4*)&bias[k * 4] = *(const float4*)&bb[lane * 16 + k * 4];
    float o[16];
    #pragma unroll
    for (int d = 0; d < 16; ++d) {
      float acc = 0.f;
      #pragma unroll
      for (int j = 0; j < 16; ++j)
        acc = fmaf(w2[d * 16 + j], t2r[j], acc);
      o[d] = acc + bias[d];
    }
    const float sc = (p == 0) ? QSCALE : 1.0f;
    #pragma unroll
    for (int h3 = 0; h3 < 4; ++h3) {
      union { _Float16 hh[4]; uint2 u; } pk;
      #pragma unroll
      for (int z = 0; z < 4; ++z)
        pk.hh[z] = (_Float16)(o[4 * z + h3] * sc);
      const int head = h1 * 8 + h2 * 4 + h3;
      *(uint2*)&op[((size_t)((b * NH + head) * S + t)) * HD + xs * 16 + ys * 4]
          = pk.u;
    }
    __builtin_amdgcn_wave_barrier();
  }
}

// ---------------------------------------------------------------------------
// Kernel A2: V [b,h,600,64] f16 -> Vt [b,h,64,600] f16 (unchanged).
// ---------------------------------------------------------------------------
__global__ __launch_bounds__(256) void vtrans_kernel(
    const _Float16* __restrict__ Vh, _Float16* __restrict__ Vt)
{
  __shared__ __align__(16) _Float16 tile[64 * 64];
  const int tid = threadIdx.x;
  const int tt = blockIdx.x, h = blockIdx.y, b = blockIdx.z;
  const size_t rbase = (size_t)(b * NH + h) * S * HD;
  const size_t wbase = (size_t)(b * NH + h) * HD * S;
  const int t0 = tt * 64;

  #pragma unroll
  for (int hp = 0; hp < 2; ++hp) {
    const int u = hp * 256 + tid;
    const int r = u >> 3, ch = u & 7;
    f16x8 v = {0, 0, 0, 0, 0, 0, 0, 0};
    if (t0 + r < S) v = *(const f16x8*)&Vh[rbase + (size_t)(t0 + r) * HD + ch * 8];
    *(f16x8*)&tile[r * 64 + ((ch ^ ((r ^ (r >> 3)) & 7)) * 8)] = v;
  }
  __syncthreads();
  #pragma unroll
  for (int hp = 0; hp < 2; ++hp) {
    const int w = hp * 256 + tid;
    const int d = w >> 3, tc = w & 7;
    if (t0 + tc * 8 + 8 <= S) {
      const int cd = d >> 3;
      union { _Float16 hh[8]; f16x8 v; } g;
      #pragma unroll
      for (int e = 0; e < 8; ++e) {
        const int r = tc * 8 + e;
        g.hh[e] = tile[r * 64 + ((cd ^ ((r ^ (r >> 3)) & 7)) * 8) + (d & 7)];
      }
      *(f16x8*)&Vt[wbase + (size_t)d * S + t0 + tc * 8] = g.v;
    }
  }
}

// ---------------------------------------------------------------------------
// Kernel B: MFMA flash attention on 32x32x16 fragments. Wave owns 32 q-rows
// (vs 16): per unit work, LDS b128 reads drop 1.8x and MFMA instrs halve —
// attacking the measured LDS-bandwidth wall (R9-R13 flat at ~67us).
// A-frag: row=lane&31, k=(lane>>5)*8+j.  B-frag: col=lane&31, same k.
// C/D: col=lane&31, row=(reg&3)+8*(reg>>2)+4*(lane>>5)  [measured m74/m101].
// Softmax: lane pair (l, l+32) co-owns q-col -> ONE shfl_xor(32) per reduce.
// P relay in two 32-key halves through per-wave [32][32] swizzled buffer.
// Staging: global_load_lds w=16, dbuf, pre-swizzled sources (as R12).
// ---------------------------------------------------------------------------
__device__ __forceinline__ void gload16(const _Float16* g, _Float16* l) {
  __builtin_amdgcn_global_load_lds(
      (const __attribute__((address_space(1))) unsigned int*)g,
      (__attribute__((address_space(3))) unsigned int*)l, 16, 0, 0);
}

#define ZERO16 {0.f,0.f,0.f,0.f,0.f,0.f,0.f,0.f,0.f,0.f,0.f,0.f,0.f,0.f,0.f,0.f}

template<bool TAIL>
__device__ __forceinline__ void attn_step32(
    const _Float16* __restrict__ Ks, const _Float16* __restrict__ Vs,
    _Float16* __restrict__ Pw,
    const f16x8 (&qf)[4],
    f32x16 (&po)[2], float& mrow, float& lrow,
    const int lq, const int lh)
{
  const int ksw = lq & 7;                  // (row&7) for K/V reads
  // --- QK^T: keyblocks {0,1} x 32 q, k-dim 64 (4 chunks) ---
  f32x16 a0 = ZERO16, a1 = ZERO16;
  __builtin_amdgcn_s_setprio(1);
  #pragma unroll
  for (int kc = 0; kc < 4; ++kc) {
    const int slot = ((kc * 2 + lh) ^ ksw) * 8;
    const f16x8 k0 = *(const f16x8*)&Ks[lq * 64 + slot];
    a0 = __builtin_amdgcn_mfma_f32_32x32x16_f16(k0, qf[kc], a0, 0, 0, 0);
    if (!TAIL) {
      const f16x8 k1 = *(const f16x8*)&Ks[(32 + lq) * 64 + slot];
      a1 = __builtin_amdgcn_mfma_f32_32x32x16_f16(k1, qf[kc], a1, 0, 0, 0);
    }
  }
  __builtin_amdgcn_s_setprio(0);
  // --- mask + row max (lane pair l/l+32 co-owns q-col lq) ---
  float sv0[16], sv1[16];
  float tmax = -1e30f;
  #pragma unroll
  for (int r = 0; r < 16; ++r) {
    float s = a0[r];
    if (TAIL && r >= 12) s = -1e30f;       // keys >= 600 dead
    sv0[r] = s;
    tmax = fmaxf(tmax, s);
  }
  if (!TAIL) {
    #pragma unroll
    for (int r = 0; r < 16; ++r) { sv1[r] = a1[r]; tmax = fmaxf(tmax, sv1[r]); }
  }
  tmax = fmaxf(tmax, __shfl_xor(tmax, 32));
  if (!__all(tmax - mrow <= 11.0f)) {      // defer-max (P <= 2^11, f16-safe)
    const float mn = fmaxf(mrow, tmax);
    const float corr = __builtin_amdgcn_exp2f(mrow - mn);
    lrow *= corr;
    po[0] *= corr;
    po[1] *= corr;
    mrow = mn;
  }
  float rs = 0.f;
  // --- half 0 (keys 0..31 of tile): exp -> P -> PV ---
  {
    _Float16 ph[16];
    #pragma unroll
    for (int r = 0; r < 16; ++r) {
      const float e = __builtin_amdgcn_exp2f(sv0[r] - mrow);
      rs += e;
      ph[r] = (_Float16)e;
    }
    #pragma unroll
    for (int g = 0; g < 4; ++g) {
      union { _Float16 hh[4]; unsigned long long u; } pk;
      pk.hh[0] = ph[4*g]; pk.hh[1] = ph[4*g+1];
      pk.hh[2] = ph[4*g+2]; pk.hh[3] = ph[4*g+3];
      *(unsigned long long*)&Pw[lq * 32 + ((g ^ (lq & 3)) * 8) + lh * 4] = pk.u;
    }
    __builtin_amdgcn_wave_barrier();       // P writes before P reads (same wave)
    __builtin_amdgcn_s_setprio(1);
    #pragma unroll
    for (int kc2 = 0; kc2 < 2; ++kc2) {
      const f16x8 pf = *(const f16x8*)
          &Pw[lq * 32 + (((kc2 * 2 + lh) ^ (lq & 3)) * 8)];
      #pragma unroll
      for (int db = 0; db < 2; ++db) {
        const f16x8 vf = *(const f16x8*)
            &Vs[(db * 32 + lq) * 64 + (((kc2 * 2 + lh) ^ ksw) * 8)];
        po[db] = __builtin_amdgcn_mfma_f32_32x32x16_f16(vf, pf, po[db], 0, 0, 0);
      }
    }
    __builtin_amdgcn_s_setprio(0);
  }
  // --- half 1 (keys 32..63) ---
  if (!TAIL) {
    __builtin_amdgcn_wave_barrier();       // PV0 reads done before P overwrite
    _Float16 ph[16];
    #pragma unroll
    for (int r = 0; r < 16; ++r) {
      const float e = __builtin_amdgcn_exp2f(sv1[r] - mrow);
      rs += e;
      ph[r] = (_Float16)e;
    }
    #pragma unroll
    for (int g = 0; g < 4; ++g) {
      union { _Float16 hh[4]; unsigned long long u; } pk;
      pk.hh[0] = ph[4*g]; pk.hh[1] = ph[4*g+1];
      pk.hh[2] = ph[4*g+2]; pk.hh[3] = ph[4*g+3];
      *(unsigned long long*)&Pw[lq * 32 + ((g ^ (lq & 3)) * 8) + lh * 4] = pk.u;
    }
    __builtin_amdgcn_wave_barrier();
    __builtin_amdgcn_s_setprio(1);
    #pragma unroll
    for (int kc2 = 0; kc2 < 2; ++kc2) {
      const f16x8 pf = *(const f16x8*)
          &Pw[lq * 32 + (((kc2 * 2 + lh) ^ (lq & 3)) * 8)];
      #pragma unroll
      for (int db = 0; db < 2; ++db) {
        const f16x8 vf = *(const f16x8*)
            &Vs[(db * 32 + lq) * 64 + (((4 + kc2 * 2 + lh) ^ ksw) * 8)];
        po[db] = __builtin_amdgcn_mfma_f32_32x32x16_f16(vf, pf, po[db], 0, 0, 0);
      }
    }
    __builtin_amdgcn_s_setprio(0);
  }
  rs += __shfl_xor(rs, 32);
  lrow += rs;
}

__global__ __launch_bounds__(256, 4) void attn_mfma_kernel(
    const _Float16* __restrict__ Qh, const _Float16* __restrict__ Kh,
    const _Float16* __restrict__ Vt, float* __restrict__ Og)
{
  __shared__ __align__(16) union {
    struct {
      _Float16 K[2][64 * 64];   // dbuf, swizzled [key][slot]  16 KB
      _Float16 V[2][64 * 64];   // dbuf, swizzled [d][slot]    16 KB
      _Float16 P[4][32 * 32];   // per-wave P relay (one half)  8 KB
    } m;                        // 40960 B -> 4 blocks/CU
    float ot[4][32 * 68];       // epilogue staging (34816 B)
  } sm;

  const int tid = threadIdx.x;
  const int lane = tid & 63;
  const int wv = tid >> 6;
  // XCD-aware decode: 1280 blocks; all 5 q-tiles of a (b,h) share an XCD.
  const int id = blockIdx.x;
  const int idx = id >> 3;
  const int bh = (id & 7) * 32 + idx / 5;
  const int qt = idx - (idx / 5) * 5;
  const size_t base  = (size_t)bh * S * HD;
  const size_t vbase = (size_t)bh * HD * S;
  const int lq = lane & 31;   // q-col / key-row / d-row
  const int lh = lane >> 5;   // k-half selector

  // Q B-fragments: qf[kc][j] = Q[qrow][kc*16 + lh*8 + j]
  const int qrow_l = qt * 128 + wv * 32 + lq;
  const int qrow = (qrow_l < S) ? qrow_l : (S - 1);
  f16x8 qf[4];
  #pragma unroll
  for (int kc = 0; kc < 4; ++kc)
    qf[kc] = *(const f16x8*)&Qh[base + (size_t)qrow * HD + kc * 16 + lh * 8];

  f32x16 po[2] = {ZERO16, ZERO16};
  float mrow = -1e30f, lrow = 0.f;

  // gload staging (as R12): wave wv owns 8-row chunks {wv, wv+4} of K and V.
  const int sr = lane >> 3, ss = lane & 7;
  const int swz8 = (ss ^ sr) * 8;
  const int c0 = wv, c1 = wv + 4;
  const _Float16* kg0 = Kh + base + (size_t)(c0 * 8 + sr) * HD + swz8;
  const _Float16* kg1 = Kh + base + (size_t)(c1 * 8 + sr) * HD + swz8;
  const _Float16* vg0 = Vt + vbase + (size_t)(c0 * 8 + sr) * S + swz8;
  const _Float16* vg1 = Vt + vbase + (size_t)(c1 * 8 + sr) * S + swz8;

  auto gload_tile = [&](int kt, int b) {
    const int kb = kt * 64;
    gload16(kg0 + (size_t)kb * HD, &sm.m.K[b][c0 * 512]);
    gload16(kg1 + (size_t)kb * HD, &sm.m.K[b][c1 * 512]);
    gload16(vg0 + kb, &sm.m.V[b][c0 * 512]);
    gload16(vg1 + kb, &sm.m.V[b][c1 * 512]);
  };

  gload_tile(0, 0);
  #pragma unroll 2
  for (int kt = 0; kt < 9; ++kt) {
    const int b = kt & 1;
    __syncthreads();              // drains tile-kt gloads; orders buf^1 WAR
    gload_tile(kt + 1, b ^ 1);    // streams during attn_step below
    attn_step32<false>(&sm.m.K[b][0], &sm.m.V[b][0], &sm.m.P[wv][0],
                       qf, po, mrow, lrow, lq, lh);
  }
  __syncthreads();                // tile-9 gloads drained (buf 1)
  // zero V slots for key-chunks 3..7 (keys 600..639: spill bytes may be
  // NaN-patterned f16; NaN * P=0 = NaN). slot(row, ch) = ch ^ (row & 7).
  for (int u = tid; u < 320; u += 256) {
    const int row = u / 5, ch = 3 + u % 5;
    *(f16x8*)&sm.m.V[1][row * 64 + ((ch ^ (row & 7)) * 8)] =
        (f16x8){0, 0, 0, 0, 0, 0, 0, 0};
  }
  __syncthreads();                // zeros visible to all waves
  attn_step32<true>(&sm.m.K[1][0], &sm.m.V[1][0], &sm.m.P[wv][0],
                    qf, po, mrow, lrow, lq, lh);
  __syncthreads();   // main-loop LDS fully consumed before epilogue reuse

  // epilogue: po -> per-wave ot[32 q][64 d] (stride 68) -> coalesced write
  const float invl = 1.0f / lrow;
  float* otw = &sm.ot[wv][0];
  #pragma unroll
  for (int db = 0; db < 2; ++db)
    #pragma unroll
    for (int g = 0; g < 4; ++g) {
      float4 v;
      v.x = po[db][4*g]   * invl;
      v.y = po[db][4*g+1] * invl;
      v.z = po[db][4*g+2] * invl;
      v.w = po[db][4*g+3] * invl;
      *(float4*)&otw[lq * 68 + db * 32 + g * 8 + lh * 4] = v;
    }
  __builtin_amdgcn_wave_barrier();   // ot writes before ot reads (same wave)
  {
    const int r = lane >> 1, half = lane & 1;
    const int gq = qt * 128 + wv * 32 + r;
    if (gq < S) {
      #pragma unroll
      for (int k2 = 0; k2 < 8; ++k2) {
        const float4 v = *(float4*)&otw[r * 68 + half * 32 + k2 * 4];
        *(float4*)&Og[base + (size_t)gq * HD + half * 32 + k2 * 4] = v;
      }
    }
  }
}

// ---------------------------------------------------------------------------
// Kernel C: output TCL — wave-per-token, barrier-free (unchanged).
// ---------------------------------------------------------------------------
__global__ __launch_bounds__(256) void tcl_out_kernel(
    const float* __restrict__ Og,
    const float* __restrict__ ow0, const float* __restrict__ ow1,
    const float* __restrict__ ow2, const float* __restrict__ ob,
    float* __restrict__ out)
{
  __shared__ __align__(16) float t1s[4][64 * LDT];
  __shared__ __align__(16) float t2s[4][64 * LDT];

  const int tid = threadIdx.x;
  const int wv = tid >> 6, lane = tid & 63;
  const int tok = blockIdx.x * 4 + wv;
  const int b = tok / S, t = tok - b * S;
  const int q = lane >> 3, zp = lane & 7;
  float* __restrict__ t1 = t1s[wv];
  float* __restrict__ t2 = t2s[wv];

  float2 xc[8];
  {
    const int h2g = q & 1, yg = q >> 1;
    const int h3g = 2 * (zp & 1), zg = zp >> 1;
    #pragma unroll
    for (int xx = 0; xx < 8; ++xx) {
      const int headb = (xx & 1) * 8 + h2g * 4 + h3g;
      const size_t off = ((size_t)((b * NH + headb) * S + t)) * HD
                       + (xx >> 1) * 16 + yg * 4 + zg;
      xc[xx].x = Og[off];
      xc[xx].y = Og[off + (size_t)S * HD];
    }
  }

  #pragma unroll
  for (int a = 0; a < 8; ++a) {
    float2 r = make_float2(0.f, 0.f);
    #pragma unroll
    for (int xx = 0; xx < 8; ++xx) {
      const float w = ow0[a * 8 + xx];
      r.x = fmaf(w, xc[xx].x, r.x);
      r.y = fmaf(w, xc[xx].y, r.y);
    }
    *(float2*)&t1[(a * 8 + q) * LDT + zp * 2] = r;
  }
  __builtin_amdgcn_wave_barrier();

  float2 t1r[8];
  #pragma unroll
  for (int y = 0; y < 8; ++y)
    t1r[y] = *(float2*)&t1[(q * 8 + y) * LDT + zp * 2];
  #pragma unroll
  for (int c = 0; c < 8; ++c) {
    float2 r = make_float2(0.f, 0.f);
    #pragma unroll
    for (int y = 0; y < 8; ++y) {
      const float w = ow1[c * 8 + y];
      r.x = fmaf(w, t1r[y].x, r.x);
      r.y = fmaf(w, t1r[y].y, r.y);
    }
    *(float2*)&t2[(q * 8 + c) * LDT + zp * 2] = r;
  }
  __builtin_amdgcn_wave_barrier();

  float t2r[16];
  #pragma unroll
  for (int k = 0; k < 4; ++k)
    *(float4*)&t2r[k * 4] = *(float4*)&t2[lane * LDT + k * 4];
  float bias[16];
  #pragma unroll
  for (int k = 0; k < 4; ++k)
    *(float4*)&bias[k * 4] = *(const float4*)&ob[lane * 16 + k * 4];
  float o[16];
  #pragma unroll
  for (int d = 0; d < 16; ++d) {
    float acc = 0.f;
    #pragma unroll
    for (int j = 0; j < 16; ++j)
      acc = fmaf(ow2[d * 16 + j], t2r[j], acc);
    o[d] = acc + bias[d];
  }
  #pragma unroll
  for (int k = 0; k < 4; ++k) {
    const float4 res = make_float4(o[4 * k], o[4 * k + 1],
                                   o[4 * k + 2], o[4 * k + 3]);
    *(float4*)&out[(size_t)tok * 1024 + lane * 16 + k * 4] = res;
  }
}

// ---------------------------------------------------------------------------
extern "C" void kernel_launch(void* const* d_in, const int* in_sizes, int n_in,
                              void* d_out, int out_size, void* d_ws, size_t ws_size,
                              hipStream_t stream) {
  const float* x   = (const float*)d_in[0];
  const float* qw0 = (const float*)d_in[1];
  const float* qw1 = (const float*)d_in[2];
  const float* qw2 = (const float*)d_in[3];
  const float* qb  = (const float*)d_in[4];
  const float* kw0 = (const float*)d_in[5];
  const float* kw1 = (const float*)d_in[6];
  const float* kw2 = (const float*)d_in[7];
  const float* kb  = (const float*)d_in[8];
  const float* vw0 = (const float*)d_in[9];
  const float* vw1 = (const float*)d_in[10];
  const float* vw2 = (const float*)d_in[11];
  const float* vb  = (const float*)d_in[12];
  const float* ow0 = (const float*)d_in[13];
  const float* ow1 = (const float*)d_in[14];
  const float* ow2 = (const float*)d_in[15];
  const float* ob  = (const float*)d_in[16];

  const size_t N = (size_t)NB * NH * S * HD;  // 9,830,400 elems per logical buffer
  _Float16* Qh  = (_Float16*)d_ws;
  _Float16* Kh  = Qh + N;
  _Float16* Vth = Kh + N;
  _Float16* Vh  = Vth + N;            // row-major V temp, later reused as O
  float*    O   = (float*)Vh;
  // total ws use: 3*N*2 + N*4 = 98.3 MB

  tcl_qkv_kernel<<<dim3(NB * S / 4), 256, 0, stream>>>(
      x, qw0, qw1, qw2, qb, kw0, kw1, kw2, kb, vw0, vw1, vw2, vb, Qh, Kh, Vh);
  vtrans_kernel<<<dim3(10, NH, NB), 256, 0, stream>>>(Vh, Vth);
  attn_mfma_kernel<<<dim3(1280), 256, 0, stream>>>(Qh, Kh, Vth, O);
  tcl_out_kernel<<<dim3(NB * S / 4), 256, 0, stream>>>(O, ow0, ow1, ow2, ob,
                                                       (float*)d_out);
}

// Round 15
// 115.584 us; speedup vs baseline: 1.1014x; 1.0310x over previous
//
#include <hip/hip_runtime.h>

// Problem constants:
//   B=16, P1=25, P2=24 -> S=600 tokens; E=(8,8,16)=1024; heads (2,2,4)=16, head_dim 64
#define S   600
#define NB  16
#define NH  16
#define HD  64
// Q pre-scale: (head_dim)^-0.5 * log2(e): scores in log2 domain -> softmax uses exp2.
#define QSCALE 0.18033688011112042f

#define LDT 20   // TCL intermediate row stride (floats)

typedef _Float16 f16x8 __attribute__((ext_vector_type(8)));
typedef float f32x4 __attribute__((ext_vector_type(4)));
typedef float f32x16 __attribute__((ext_vector_type(16)));

// ---------------------------------------------------------------------------
// Kernel A: TCL for q,k,v — wave-per-token, barrier-free (unchanged).
// ---------------------------------------------------------------------------
__global__ __launch_bounds__(256) void tcl_qkv_kernel(
    const float* __restrict__ x,
    const float* __restrict__ qw0, const float* __restrict__ qw1,
    const float* __restrict__ qw2, const float* __restrict__ qb,
    const float* __restrict__ kw0, const float* __restrict__ kw1,
    const float* __restrict__ kw2, const float* __restrict__ kb,
    const float* __restrict__ vw0, const float* __restrict__ vw1,
    const float* __restrict__ vw2, const float* __restrict__ vb,
    _Float16* __restrict__ Qh, _Float16* __restrict__ Kh,
    _Float16* __restrict__ Vh)
{
  __shared__ __align__(16) float t1s[4][64 * LDT];
  __shared__ __align__(16) float t2s[4][64 * LDT];

  const int tid = threadIdx.x;
  const int wv = tid >> 6, lane = tid & 63;
  const int tok = blockIdx.x * 4 + wv;
  const int b = tok / S, t = tok - b * S;
  const int q = lane >> 3, zp = lane & 7;
  float* __restrict__ t1 = t1s[wv];
  float* __restrict__ t2 = t2s[wv];

  float2 xc[8];
  #pragma unroll
  for (int xx = 0; xx < 8; ++xx)
    xc[xx] = *(const float2*)&x[(size_t)tok * 1024 + xx * 128 + q * 16 + zp * 2];

  const int xs = lane >> 4;
  const int h1 = (lane >> 3) & 1;
  const int cc = lane & 7;
  const int ys = cc >> 1, h2 = cc & 1;

  const float* W0[3] = {qw0, kw0, vw0};
  const float* W1[3] = {qw1, kw1, vw1};
  const float* W2[3] = {qw2, kw2, vw2};
  const float* BB[3] = {qb, kb, vb};
  _Float16* OUT[3] = {Qh, Kh, Vh};

  #pragma unroll
  for (int p = 0; p < 3; ++p) {
    const float* __restrict__ w0 = W0[p];
    const float* __restrict__ w1 = W1[p];
    const float* __restrict__ w2 = W2[p];
    const float* __restrict__ bb = BB[p];
    _Float16* __restrict__ op = OUT[p];

    #pragma unroll
    for (int a = 0; a < 8; ++a) {
      float2 r = make_float2(0.f, 0.f);
      #pragma unroll
      for (int xx = 0; xx < 8; ++xx) {
        const float w = w0[a * 8 + xx];
        r.x = fmaf(w, xc[xx].x, r.x);
        r.y = fmaf(w, xc[xx].y, r.y);
      }
      *(float2*)&t1[(a * 8 + q) * LDT + zp * 2] = r;
    }
    __builtin_amdgcn_wave_barrier();

    float2 t1r[8];
    #pragma unroll
    for (int y = 0; y < 8; ++y)
      t1r[y] = *(float2*)&t1[(q * 8 + y) * LDT + zp * 2];
    #pragma unroll
    for (int c = 0; c < 8; ++c) {
      float2 r = make_float2(0.f, 0.f);
      #pragma unroll
      for (int y = 0; y < 8; ++y) {
        const float w = w1[c * 8 + y];
        r.x = fmaf(w, t1r[y].x, r.x);
        r.y = fmaf(w, t1r[y].y, r.y);
      }
      *(float2*)&t2[(q * 8 + c) * LDT + zp * 2] = r;
    }
    __builtin_amdgcn_wave_barrier();

    float t2r[16];
    #pragma unroll
    for (int k = 0; k < 4; ++k)
      *(float4*)&t2r[k * 4] = *(float4*)&t2[lane * LDT + k * 4];
    float bias[16];
    #pragma unroll
    for (int k = 0; k < 4; ++k)
      *(float4*)&bias[k * 4] = *(const float4*)&bb[lane * 16 + k * 4];
    float o[16];
    #pragma unroll
    for (int d = 0; d < 16; ++d) {
      float acc = 0.f;
      #pragma unroll
      for (int j = 0; j < 16; ++j)
        acc = fmaf(w2[d * 16 + j], t2r[j], acc);
      o[d] = acc + bias[d];
    }
    const float sc = (p == 0) ? QSCALE : 1.0f;
    #pragma unroll
    for (int h3 = 0; h3 < 4; ++h3) {
      union { _Float16 hh[4]; uint2 u; } pk;
      #pragma unroll
      for (int z = 0; z < 4; ++z)
        pk.hh[z] = (_Float16)(o[4 * z + h3] * sc);
      const int head = h1 * 8 + h2 * 4 + h3;
      *(uint2*)&op[((size_t)((b * NH + head) * S + t)) * HD + xs * 16 + ys * 4]
          = pk.u;
    }
    __builtin_amdgcn_wave_barrier();
  }
}

// ---------------------------------------------------------------------------
// Kernel A2: V [b,h,600,64] f16 -> Vt [b,h,64,600] f16 (unchanged).
// ---------------------------------------------------------------------------
__global__ __launch_bounds__(256) void vtrans_kernel(
    const _Float16* __restrict__ Vh, _Float16* __restrict__ Vt)
{
  __shared__ __align__(16) _Float16 tile[64 * 64];
  const int tid = threadIdx.x;
  const int tt = blockIdx.x, h = blockIdx.y, b = blockIdx.z;
  const size_t rbase = (size_t)(b * NH + h) * S * HD;
  const size_t wbase = (size_t)(b * NH + h) * HD * S;
  const int t0 = tt * 64;

  #pragma unroll
  for (int hp = 0; hp < 2; ++hp) {
    const int u = hp * 256 + tid;
    const int r = u >> 3, ch = u & 7;
    f16x8 v = {0, 0, 0, 0, 0, 0, 0, 0};
    if (t0 + r < S) v = *(const f16x8*)&Vh[rbase + (size_t)(t0 + r) * HD + ch * 8];
    *(f16x8*)&tile[r * 64 + ((ch ^ ((r ^ (r >> 3)) & 7)) * 8)] = v;
  }
  __syncthreads();
  #pragma unroll
  for (int hp = 0; hp < 2; ++hp) {
    const int w = hp * 256 + tid;
    const int d = w >> 3, tc = w & 7;
    if (t0 + tc * 8 + 8 <= S) {
      const int cd = d >> 3;
      union { _Float16 hh[8]; f16x8 v; } g;
      #pragma unroll
      for (int e = 0; e < 8; ++e) {
        const int r = tc * 8 + e;
        g.hh[e] = tile[r * 64 + ((cd ^ ((r ^ (r >> 3)) & 7)) * 8) + (d & 7)];
      }
      *(f16x8*)&Vt[wbase + (size_t)d * S + t0 + tc * 8] = g.v;
    }
  }
}

// ---------------------------------------------------------------------------
// Kernel B: MFMA flash attention, 32x32x16 frags + SLAB LDS layouts.
// All LDS accesses are 16B-per-lane CONTIGUOUS (no swizzle, no conflicts):
//   K slab: [d-chunk ch][key 0..63][8 f16]  (8 x 1KB; gload: lane <-> key)
//   V slab: [key-chunk][d 0..63][8 f16]     (8 x 1KB; gload: lane <-> d)
//   P slab: [chunk g][q 0..31][8 f16]       (per wave, 2KB)
// A-frag (row=lane&31) reads slab+lq*16B -> 512B contiguous per half-wave.
// D-frag regs 4g..4g+3 = 4 consecutive keys of chunk g -> one b64 P write.
// ---------------------------------------------------------------------------
__device__ __forceinline__ void gload16(const _Float16* g, _Float16* l) {
  __builtin_amdgcn_global_load_lds(
      (const __attribute__((address_space(1))) unsigned int*)g,
      (__attribute__((address_space(3))) unsigned int*)l, 16, 0, 0);
}

#define ZERO16 {0.f,0.f,0.f,0.f,0.f,0.f,0.f,0.f,0.f,0.f,0.f,0.f,0.f,0.f,0.f,0.f}

template<bool TAIL>
__device__ __forceinline__ void attn_step32(
    const _Float16* __restrict__ Ks, const _Float16* __restrict__ Vs,
    _Float16* __restrict__ Pw,
    const f16x8 (&qf)[4],
    f32x16 (&po)[2], float& mrow, float& lrow,
    const int lq, const int lh)
{
  // --- QK^T: keyblocks {0,1} x 32 q, k-dim 64 (4 chunk-pairs) ---
  f32x16 a0 = ZERO16, a1 = ZERO16;
  __builtin_amdgcn_s_setprio(1);
  #pragma unroll
  for (int kc = 0; kc < 4; ++kc) {
    const int chb = (kc * 2 + lh) * 512;   // slab base (f16 units)
    const f16x8 k0 = *(const f16x8*)&Ks[chb + lq * 8];
    a0 = __builtin_amdgcn_mfma_f32_32x32x16_f16(k0, qf[kc], a0, 0, 0, 0);
    if (!TAIL) {
      const f16x8 k1 = *(const f16x8*)&Ks[chb + 256 + lq * 8];
      a1 = __builtin_amdgcn_mfma_f32_32x32x16_f16(k1, qf[kc], a1, 0, 0, 0);
    }
  }
  __builtin_amdgcn_s_setprio(0);
  // --- mask + row max (lane pair l/l+32 co-owns q-col lq) ---
  float sv0[16], sv1[16];
  float tmax = -1e30f;
  #pragma unroll
  for (int r = 0; r < 16; ++r) {
    float s = a0[r];
    if (TAIL && r >= 12) s = -1e30f;       // keys >= 600 dead
    sv0[r] = s;
    tmax = fmaxf(tmax, s);
  }
  if (!TAIL) {
    #pragma unroll
    for (int r = 0; r < 16; ++r) { sv1[r] = a1[r]; tmax = fmaxf(tmax, sv1[r]); }
  }
  tmax = fmaxf(tmax, __shfl_xor(tmax, 32));
  if (!__all(tmax - mrow <= 11.0f)) {      // defer-max (P <= 2^11, f16-safe)
    const float mn = fmaxf(mrow, tmax);
    const float corr = __builtin_amdgcn_exp2f(mrow - mn);
    lrow *= corr;
    po[0] *= corr;
    po[1] *= corr;
    mrow = mn;
  }
  float rs = 0.f;
  // --- half 0 (keys 0..31): exp -> P slab -> PV ---
  {
    _Float16 ph[16];
    #pragma unroll
    for (int r = 0; r < 16; ++r) {
      const float e = __builtin_amdgcn_exp2f(sv0[r] - mrow);
      rs += e;
      ph[r] = (_Float16)e;
    }
    #pragma unroll
    for (int g = 0; g < 4; ++g) {
      union { _Float16 hh[4]; unsigned long long u; } pk;
      pk.hh[0] = ph[4*g]; pk.hh[1] = ph[4*g+1];
      pk.hh[2] = ph[4*g+2]; pk.hh[3] = ph[4*g+3];
      *(unsigned long long*)&Pw[g * 256 + lq * 8 + lh * 4] = pk.u;
    }
    __builtin_amdgcn_wave_barrier();       // P writes before P reads (same wave)
    __builtin_amdgcn_s_setprio(1);
    #pragma unroll
    for (int kc2 = 0; kc2 < 2; ++kc2) {
      const int ch = 2 * kc2 + lh;
      const f16x8 pf = *(const f16x8*)&Pw[ch * 256 + lq * 8];
      #pragma unroll
      for (int db = 0; db < 2; ++db) {
        const f16x8 vf = *(const f16x8*)
            &Vs[ch * 512 + (db * 32 + lq) * 8];
        po[db] = __builtin_amdgcn_mfma_f32_32x32x16_f16(vf, pf, po[db], 0, 0, 0);
      }
    }
    __builtin_amdgcn_s_setprio(0);
  }
  // --- half 1 (keys 32..63) ---
  if (!TAIL) {
    __builtin_amdgcn_wave_barrier();       // PV0 reads done before P overwrite
    _Float16 ph[16];
    #pragma unroll
    for (int r = 0; r < 16; ++r) {
      const float e = __builtin_amdgcn_exp2f(sv1[r] - mrow);
      rs += e;
      ph[r] = (_Float16)e;
    }
    #pragma unroll
    for (int g = 0; g < 4; ++g) {
      union { _Float16 hh[4]; unsigned long long u; } pk;
      pk.hh[0] = ph[4*g]; pk.hh[1] = ph[4*g+1];
      pk.hh[2] = ph[4*g+2]; pk.hh[3] = ph[4*g+3];
      *(unsigned long long*)&Pw[g * 256 + lq * 8 + lh * 4] = pk.u;
    }
    __builtin_amdgcn_wave_barrier();
    __builtin_amdgcn_s_setprio(1);
    #pragma unroll
    for (int kc2 = 0; kc2 < 2; ++kc2) {
      const int ch = 2 * kc2 + lh;
      const f16x8 pf = *(const f16x8*)&Pw[ch * 256 + lq * 8];
      #pragma unroll
      for (int db = 0; db < 2; ++db) {
        const f16x8 vf = *(const f16x8*)
            &Vs[(4 + ch) * 512 + (db * 32 + lq) * 8];
        po[db] = __builtin_amdgcn_mfma_f32_32x32x16_f16(vf, pf, po[db], 0, 0, 0);
      }
    }
    __builtin_amdgcn_s_setprio(0);
  }
  rs += __shfl_xor(rs, 32);
  lrow += rs;
}

__global__ __launch_bounds__(256, 4) void attn_mfma_kernel(
    const _Float16* __restrict__ Qh, const _Float16* __restrict__ Kh,
    const _Float16* __restrict__ Vt, float* __restrict__ Og)
{
  __shared__ __align__(16) union {
    struct {
      _Float16 K[2][8 * 512];   // dbuf, slabs [ch][key][8]   16 KB
      _Float16 V[2][8 * 512];   // dbuf, slabs [kch][d][8]    16 KB
      _Float16 P[4][4 * 256];   // per-wave P slabs [g][q][8]  8 KB
    } m;                        // 40960 B -> 4 blocks/CU
    float ot[4][32 * 68];       // epilogue staging (34816 B)
  } sm;

  const int tid = threadIdx.x;
  const int lane = tid & 63;
  const int wv = tid >> 6;
  // XCD-aware decode: 1280 blocks; all 5 q-tiles of a (b,h) share an XCD.
  const int id = blockIdx.x;
  const int idx = id >> 3;
  const int bh = (id & 7) * 32 + idx / 5;
  const int qt = idx - (idx / 5) * 5;
  const size_t base  = (size_t)bh * S * HD;
  const size_t vbase = (size_t)bh * HD * S;
  const int lq = lane & 31;   // q-col / key-row / d-row
  const int lh = lane >> 5;   // k-half selector

  // Q B-fragments: qf[kc][j] = Q[qrow][kc*16 + lh*8 + j]
  const int qrow_l = qt * 128 + wv * 32 + lq;
  const int qrow = (qrow_l < S) ? qrow_l : (S - 1);
  f16x8 qf[4];
  #pragma unroll
  for (int kc = 0; kc < 4; ++kc)
    qf[kc] = *(const f16x8*)&Qh[base + (size_t)qrow * HD + kc * 16 + lh * 8];

  f32x16 po[2] = {ZERO16, ZERO16};
  float mrow = -1e30f, lrow = 0.f;

  // Slab gload staging: wave wv fills K-slabs {wv, wv+4} (lane <-> key) and
  // V-slabs {wv, wv+4} (lane <-> d). Sources advance per tile.
  const _Float16* kg = Kh + base + (size_t)lane * HD + wv * 8;    // +32 for wv+4
  const _Float16* vg = Vt + vbase + (size_t)lane * S + wv * 8;    // +32 for wv+4

  auto gload_tile = [&](int kt, int b) {
    const _Float16* kp = kg + (size_t)kt * 64 * HD;
    const _Float16* vp = vg + kt * 64;
    gload16(kp,      &sm.m.K[b][wv * 512]);
    gload16(kp + 32, &sm.m.K[b][(wv + 4) * 512]);
    gload16(vp,      &sm.m.V[b][wv * 512]);
    gload16(vp + 32, &sm.m.V[b][(wv + 4) * 512]);
  };

  gload_tile(0, 0);
  #pragma unroll 2
  for (int kt = 0; kt < 9; ++kt) {
    const int b = kt & 1;
    __syncthreads();              // drains tile-kt gloads; orders buf^1 WAR
    gload_tile(kt + 1, b ^ 1);    // streams during attn_step below
    attn_step32<false>(&sm.m.K[b][0], &sm.m.V[b][0], &sm.m.P[wv][0],
                       qf, po, mrow, lrow, lq, lh);
  }
  __syncthreads();                // tile-9 gloads drained (buf 1)
  // zero V slab 3 of buf 1 (keys 600..607 garbage; NaN * P=0 = NaN).
  // Slabs 4..7 are never read in the tail step.
  if (tid < 64)
    *(f16x8*)&sm.m.V[1][3 * 512 + tid * 8] = (f16x8){0,0,0,0,0,0,0,0};
  __syncthreads();                // zeros visible to all waves
  attn_step32<true>(&sm.m.K[1][0], &sm.m.V[1][0], &sm.m.P[wv][0],
                    qf, po, mrow, lrow, lq, lh);
  __syncthreads();   // main-loop LDS fully consumed before epilogue reuse

  // epilogue: po -> per-wave ot[32 q][64 d] (stride 68) -> coalesced write
  const float invl = 1.0f / lrow;
  float* otw = &sm.ot[wv][0];
  #pragma unroll
  for (int db = 0; db < 2; ++db)
    #pragma unroll
    for (int g = 0; g < 4; ++g) {
      float4 v;
      v.x = po[db][4*g]   * invl;
      v.y = po[db][4*g+1] * invl;
      v.z = po[db][4*g+2] * invl;
      v.w = po[db][4*g+3] * invl;
      *(float4*)&otw[lq * 68 + db * 32 + g * 8 + lh * 4] = v;
    }
  __builtin_amdgcn_wave_barrier();   // ot writes before ot reads (same wave)
  {
    const int r = lane >> 1, half = lane & 1;
    const int gq = qt * 128 + wv * 32 + r;
    if (gq < S) {
      #pragma unroll
      for (int k2 = 0; k2 < 8; ++k2) {
        const float4 v = *(float4*)&otw[r * 68 + half * 32 + k2 * 4];
        *(float4*)&Og[base + (size_t)gq * HD + half * 32 + k2 * 4] = v;
      }
    }
  }
}

// ---------------------------------------------------------------------------
// Kernel C: output TCL — wave-per-token, barrier-free (unchanged).
// ---------------------------------------------------------------------------
__global__ __launch_bounds__(256) void tcl_out_kernel(
    const float* __restrict__ Og,
    const float* __restrict__ ow0, const float* __restrict__ ow1,
    const float* __restrict__ ow2, const float* __restrict__ ob,
    float* __restrict__ out)
{
  __shared__ __align__(16) float t1s[4][64 * LDT];
  __shared__ __align__(16) float t2s[4][64 * LDT];

  const int tid = threadIdx.x;
  const int wv = tid >> 6, lane = tid & 63;
  const int tok = blockIdx.x * 4 + wv;
  const int b = tok / S, t = tok - b * S;
  const int q = lane >> 3, zp = lane & 7;
  float* __restrict__ t1 = t1s[wv];
  float* __restrict__ t2 = t2s[wv];

  float2 xc[8];
  {
    const int h2g = q & 1, yg = q >> 1;
    const int h3g = 2 * (zp & 1), zg = zp >> 1;
    #pragma unroll
    for (int xx = 0; xx < 8; ++xx) {
      const int headb = (xx & 1) * 8 + h2g * 4 + h3g;
      const size_t off = ((size_t)((b * NH + headb) * S + t)) * HD
                       + (xx >> 1) * 16 + yg * 4 + zg;
      xc[xx].x = Og[off];
      xc[xx].y = Og[off + (size_t)S * HD];
    }
  }

  #pragma unroll
  for (int a = 0; a < 8; ++a) {
    float2 r = make_float2(0.f, 0.f);
    #pragma unroll
    for (int xx = 0; xx < 8; ++xx) {
      const float w = ow0[a * 8 + xx];
      r.x = fmaf(w, xc[xx].x, r.x);
      r.y = fmaf(w, xc[xx].y, r.y);
    }
    *(float2*)&t1[(a * 8 + q) * LDT + zp * 2] = r;
  }
  __builtin_amdgcn_wave_barrier();

  float2 t1r[8];
  #pragma unroll
  for (int y = 0; y < 8; ++y)
    t1r[y] = *(float2*)&t1[(q * 8 + y) * LDT + zp * 2];
  #pragma unroll
  for (int c = 0; c < 8; ++c) {
    float2 r = make_float2(0.f, 0.f);
    #pragma unroll
    for (int y = 0; y < 8; ++y) {
      const float w = ow1[c * 8 + y];
      r.x = fmaf(w, t1r[y].x, r.x);
      r.y = fmaf(w, t1r[y].y, r.y);
    }
    *(float2*)&t2[(q * 8 + c) * LDT + zp * 2] = r;
  }
  __builtin_amdgcn_wave_barrier();

  float t2r[16];
  #pragma unroll
  for (int k = 0; k < 4; ++k)
    *(float4*)&t2r[k * 4] = *(float4*)&t2[lane * LDT + k * 4];
  float bias[16];
  #pragma unroll
  for (int k = 0; k < 4; ++k)
    *(float4*)&bias[k * 4] = *(const float4*)&ob[lane * 16 + k * 4];
  float o[16];
  #pragma unroll
  for (int d = 0; d < 16; ++d) {
    float acc = 0.f;
    #pragma unroll
    for (int j = 0; j < 16; ++j)
      acc = fmaf(ow2[d * 16 + j], t2r[j], acc);
    o[d] = acc + bias[d];
  }
  #pragma unroll
  for (int k = 0; k < 4; ++k) {
    const float4 res = make_float4(o[4 * k], o[4 * k + 1],
                                   o[4 * k + 2], o[4 * k + 3]);
    *(float4*)&out[(size_t)tok * 1024 + lane * 16 + k * 4] = res;
  }
}

// ---------------------------------------------------------------------------
extern "C" void kernel_launch(void* const* d_in, const int* in_sizes, int n_in,
                              void* d_out, int out_size, void* d_ws, size_t ws_size,
                              hipStream_t stream) {
  const float* x   = (const float*)d_in[0];
  const float* qw0 = (const float*)d_in[1];
  const float* qw1 = (const float*)d_in[2];
  const float* qw2 = (const float*)d_in[3];
  const float* qb  = (const float*)d_in[4];
  const float* kw0 = (const float*)d_in[5];
  const float* kw1 = (const float*)d_in[6];
  const float* kw2 = (const float*)d_in[7];
  const float* kb  = (const float*)d_in[8];
  const float* vw0 = (const float*)d_in[9];
  const float* vw1 = (const float*)d_in[10];
  const float* vw2 = (const float*)d_in[11];
  const float* vb  = (const float*)d_in[12];
  const float* ow0 = (const float*)d_in[13];
  const float* ow1 = (const float*)d_in[14];
  const float* ow2 = (const float*)d_in[15];
  const float* ob  = (const float*)d_in[16];

  const size_t N = (size_t)NB * NH * S * HD;  // 9,830,400 elems per logical buffer
  _Float16* Qh  = (_Float16*)d_ws;
  _Float16* Kh  = Qh + N;
  _Float16* Vth = Kh + N;
  _Float16* Vh  = Vth + N;            // row-major V temp, later reused as O
  float*    O   = (float*)Vh;
  // total ws use: 3*N*2 + N*4 = 98.3 MB

  tcl_qkv_kernel<<<dim3(NB * S / 4), 256, 0, stream>>>(
      x, qw0, qw1, qw2, qb, kw0, kw1, kw2, kb, vw0, vw1, vw2, vb, Qh, Kh, Vh);
  vtrans_kernel<<<dim3(10, NH, NB), 256, 0, stream>>>(Vh, Vth);
  attn_mfma_kernel<<<dim3(1280), 256, 0, stream>>>(Qh, Kh, Vth, O);
  tcl_out_kernel<<<dim3(NB * S / 4), 256, 0, stream>>>(O, ow0, ow1, ow2, ob,
                                                       (float*)d_out);
}

// Round 17
// 114.149 us; speedup vs baseline: 1.1153x; 1.0126x over previous
//
#include <hip/hip_runtime.h>

// Problem constants:
//   B=16, P1=25, P2=24 -> S=600 tokens; E=(8,8,16)=1024; heads (2,2,4)=16, head_dim 64
#define S   600
#define NB  16
#define NH  16
#define HD  64
// Q pre-scale: (head_dim)^-0.5 * log2(e): scores in log2 domain -> softmax uses exp2.
#define QSCALE 0.18033688011112042f

#define LDT 20   // TCL intermediate row stride (floats)

typedef _Float16 f16x8 __attribute__((ext_vector_type(8)));
typedef __fp16 fp16x2 __attribute__((ext_vector_type(2)));
typedef float f32x4 __attribute__((ext_vector_type(4)));
typedef float f32x16 __attribute__((ext_vector_type(16)));
typedef int v2i __attribute__((ext_vector_type(2)));
typedef unsigned int u32;

// ---------------------------------------------------------------------------
// Kernel A: TCL for q,k,v — wave-per-token, barrier-free (unchanged).
// ---------------------------------------------------------------------------
__global__ __launch_bounds__(256) void tcl_qkv_kernel(
    const float* __restrict__ x,
    const float* __restrict__ qw0, const float* __restrict__ qw1,
    const float* __restrict__ qw2, const float* __restrict__ qb,
    const float* __restrict__ kw0, const float* __restrict__ kw1,
    const float* __restrict__ kw2, const float* __restrict__ kb,
    const float* __restrict__ vw0, const float* __restrict__ vw1,
    const float* __restrict__ vw2, const float* __restrict__ vb,
    _Float16* __restrict__ Qh, _Float16* __restrict__ Kh,
    _Float16* __restrict__ Vh)
{
  __shared__ __align__(16) float t1s[4][64 * LDT];
  __shared__ __align__(16) float t2s[4][64 * LDT];

  const int tid = threadIdx.x;
  const int wv = tid >> 6, lane = tid & 63;
  const int tok = blockIdx.x * 4 + wv;
  const int b = tok / S, t = tok - b * S;
  const int q = lane >> 3, zp = lane & 7;
  float* __restrict__ t1 = t1s[wv];
  float* __restrict__ t2 = t2s[wv];

  float2 xc[8];
  #pragma unroll
  for (int xx = 0; xx < 8; ++xx)
    xc[xx] = *(const float2*)&x[(size_t)tok * 1024 + xx * 128 + q * 16 + zp * 2];

  const int xs = lane >> 4;
  const int h1 = (lane >> 3) & 1;
  const int cc = lane & 7;
  const int ys = cc >> 1, h2 = cc & 1;

  const float* W0[3] = {qw0, kw0, vw0};
  const float* W1[3] = {qw1, kw1, vw1};
  const float* W2[3] = {qw2, kw2, vw2};
  const float* BB[3] = {qb, kb, vb};
  _Float16* OUT[3] = {Qh, Kh, Vh};

  #pragma unroll
  for (int p = 0; p < 3; ++p) {
    const float* __restrict__ w0 = W0[p];
    const float* __restrict__ w1 = W1[p];
    const float* __restrict__ w2 = W2[p];
    const float* __restrict__ bb = BB[p];
    _Float16* __restrict__ op = OUT[p];

    #pragma unroll
    for (int a = 0; a < 8; ++a) {
      float2 r = make_float2(0.f, 0.f);
      #pragma unroll
      for (int xx = 0; xx < 8; ++xx) {
        const float w = w0[a * 8 + xx];
        r.x = fmaf(w, xc[xx].x, r.x);
        r.y = fmaf(w, xc[xx].y, r.y);
      }
      *(float2*)&t1[(a * 8 + q) * LDT + zp * 2] = r;
    }
    __builtin_amdgcn_wave_barrier();

    float2 t1r[8];
    #pragma unroll
    for (int y = 0; y < 8; ++y)
      t1r[y] = *(float2*)&t1[(q * 8 + y) * LDT + zp * 2];
    #pragma unroll
    for (int c = 0; c < 8; ++c) {
      float2 r = make_float2(0.f, 0.f);
      #pragma unroll
      for (int y = 0; y < 8; ++y) {
        const float w = w1[c * 8 + y];
        r.x = fmaf(w, t1r[y].x, r.x);
        r.y = fmaf(w, t1r[y].y, r.y);
      }
      *(float2*)&t2[(q * 8 + c) * LDT + zp * 2] = r;
    }
    __builtin_amdgcn_wave_barrier();

    float t2r[16];
    #pragma unroll
    for (int k = 0; k < 4; ++k)
      *(float4*)&t2r[k * 4] = *(float4*)&t2[lane * LDT + k * 4];
    float bias[16];
    #pragma unroll
    for (int k = 0; k < 4; ++k)
      *(float4*)&bias[k * 4] = *(const float4*)&bb[lane * 16 + k * 4];
    float o[16];
    #pragma unroll
    for (int d = 0; d < 16; ++d) {
      float acc = 0.f;
      #pragma unroll
      for (int j = 0; j < 16; ++j)
        acc = fmaf(w2[d * 16 + j], t2r[j], acc);
      o[d] = acc + bias[d];
    }
    const float sc = (p == 0) ? QSCALE : 1.0f;
    #pragma unroll
    for (int h3 = 0; h3 < 4; ++h3) {
      union { _Float16 hh[4]; uint2 u; } pk;
      #pragma unroll
      for (int z = 0; z < 4; ++z)
        pk.hh[z] = (_Float16)(o[4 * z + h3] * sc);
      const int head = h1 * 8 + h2 * 4 + h3;
      *(uint2*)&op[((size_t)((b * NH + head) * S + t)) * HD + xs * 16 + ys * 4]
          = pk.u;
    }
    __builtin_amdgcn_wave_barrier();
  }
}

// ---------------------------------------------------------------------------
// Kernel A2: V [b,h,600,64] f16 -> Vt [b,h,64,600] f16 (unchanged).
// ---------------------------------------------------------------------------
__global__ __launch_bounds__(256) void vtrans_kernel(
    const _Float16* __restrict__ Vh, _Float16* __restrict__ Vt)
{
  __shared__ __align__(16) _Float16 tile[64 * 64];
  const int tid = threadIdx.x;
  const int tt = blockIdx.x, h = blockIdx.y, b = blockIdx.z;
  const size_t rbase = (size_t)(b * NH + h) * S * HD;
  const size_t wbase = (size_t)(b * NH + h) * HD * S;
  const int t0 = tt * 64;

  #pragma unroll
  for (int hp = 0; hp < 2; ++hp) {
    const int u = hp * 256 + tid;
    const int r = u >> 3, ch = u & 7;
    f16x8 v = {0, 0, 0, 0, 0, 0, 0, 0};
    if (t0 + r < S) v = *(const f16x8*)&Vh[rbase + (size_t)(t0 + r) * HD + ch * 8];
    *(f16x8*)&tile[r * 64 + ((ch ^ ((r ^ (r >> 3)) & 7)) * 8)] = v;
  }
  __syncthreads();
  #pragma unroll
  for (int hp = 0; hp < 2; ++hp) {
    const int w = hp * 256 + tid;
    const int d = w >> 3, tc = w & 7;
    if (t0 + tc * 8 + 8 <= S) {
      const int cd = d >> 3;
      union { _Float16 hh[8]; f16x8 v; } g;
      #pragma unroll
      for (int e = 0; e < 8; ++e) {
        const int r = tc * 8 + e;
        g.hh[e] = tile[r * 64 + ((cd ^ ((r ^ (r >> 3)) & 7)) * 8) + (d & 7)];
      }
      *(f16x8*)&Vt[wbase + (size_t)d * S + t0 + tc * 8] = g.v;
    }
  }
}

// ---------------------------------------------------------------------------
// Kernel B: MFMA flash attention, 32x32x16 frags + slab LDS + IN-REGISTER
// P redistribution (T12). QK^T D-frag: col=q=lane&31, row(key) =
// (r&3)+8*(r>>2)+4*lh. The PV B-frag (k = kc2*16+lh*8+j) needs the partner
// lane's (lane^32) key-pairs; cvt_pkrtz packs adjacent keys, ONE
// permlane32_swap delivers both output words (vdst-hi <-> src-lo):
//   r = swap(A0,B0): r0 = lane<32 ? A0self : B0partner  (frag w0)
//                    r1 = lane<32 ? A0partner : B0self  (frag w2)
// This deletes the entire P LDS relay (12 ops + 4 fences per tile).
// ---------------------------------------------------------------------------
__device__ __forceinline__ void gload16(const _Float16* g, _Float16* l) {
  __builtin_amdgcn_global_load_lds(
      (const __attribute__((address_space(1))) unsigned int*)g,
      (__attribute__((address_space(3))) unsigned int*)l, 16, 0, 0);
}

__device__ __forceinline__ u32 pk2(float lo, float hi) {
  union { fp16x2 h; u32 u; } c;
  c.h = __builtin_amdgcn_cvt_pkrtz(lo, hi);
  return c.u;
}

// Assemble PV B-frag from packed key-pair words (A0,A1 = this lane-half's
// first pair-block; B0,B1 = its second). See header comment for mapping.
__device__ __forceinline__ f16x8 pfrag(u32 A0, u32 A1, u32 B0, u32 B1) {
  const v2i r = __builtin_amdgcn_permlane32_swap((int)A0, (int)B0, false, false);
  const v2i s = __builtin_amdgcn_permlane32_swap((int)A1, (int)B1, false, false);
  union { u32 w[4]; f16x8 v; } u;
  u.w[0] = (u32)r[0]; u.w[1] = (u32)s[0];
  u.w[2] = (u32)r[1]; u.w[3] = (u32)s[1];
  return u.v;
}

#define ZERO16 {0.f,0.f,0.f,0.f,0.f,0.f,0.f,0.f,0.f,0.f,0.f,0.f,0.f,0.f,0.f,0.f}

template<bool TAIL>
__device__ __forceinline__ void attn_step32(
    const _Float16* __restrict__ Ks, const _Float16* __restrict__ Vs,
    const f16x8 (&qf)[4],
    f32x16 (&po)[2], float& mrow, float& lrow,
    const int lq, const int lh)
{
  // --- QK^T: keyblocks {0,1} x 32 q, k-dim 64 (4 chunk-pairs) ---
  f32x16 a0 = ZERO16, a1 = ZERO16;
  __builtin_amdgcn_s_setprio(1);
  #pragma unroll
  for (int kc = 0; kc < 4; ++kc) {
    const int chb = (kc * 2 + lh) * 512;   // slab base (f16 units)
    const f16x8 k0 = *(const f16x8*)&Ks[chb + lq * 8];
    a0 = __builtin_amdgcn_mfma_f32_32x32x16_f16(k0, qf[kc], a0, 0, 0, 0);
    if (!TAIL) {
      const f16x8 k1 = *(const f16x8*)&Ks[chb + 256 + lq * 8];
      a1 = __builtin_amdgcn_mfma_f32_32x32x16_f16(k1, qf[kc], a1, 0, 0, 0);
    }
  }
  __builtin_amdgcn_s_setprio(0);
  // --- mask + row max (lane pair l/l+32 co-owns q-col lq) ---
  float sv0[16], sv1[16];
  float tmax = -1e30f;
  #pragma unroll
  for (int r = 0; r < 16; ++r) {
    float s = a0[r];
    if (TAIL && r >= 12) s = -1e30f;       // keys >= 600 dead
    sv0[r] = s;
    tmax = fmaxf(tmax, s);
  }
  if (!TAIL) {
    #pragma unroll
    for (int r = 0; r < 16; ++r) { sv1[r] = a1[r]; tmax = fmaxf(tmax, sv1[r]); }
  }
  tmax = fmaxf(tmax, __shfl_xor(tmax, 32));
  if (!__all(tmax - mrow <= 11.0f)) {      // defer-max (P <= 2^11, f16-safe)
    const float mn = fmaxf(mrow, tmax);
    const float corr = __builtin_amdgcn_exp2f(mrow - mn);
    lrow *= corr;
    po[0] *= corr;
    po[1] *= corr;
    mrow = mn;
  }
  float rs = 0.f;
  // --- half 0 (keys 0..31): exp -> in-reg P frags -> PV ---
  {
    float e[16];
    #pragma unroll
    for (int r = 0; r < 16; ++r) {
      e[r] = __builtin_amdgcn_exp2f(sv0[r] - mrow);
      rs += e[r];
    }
    f16x8 pf0 = pfrag(pk2(e[0], e[1]),  pk2(e[2], e[3]),
                      pk2(e[4], e[5]),  pk2(e[6], e[7]));
    f16x8 pf1 = pfrag(pk2(e[8], e[9]),  pk2(e[10], e[11]),
                      pk2(e[12], e[13]), pk2(e[14], e[15]));
    __builtin_amdgcn_s_setprio(1);
    #pragma unroll
    for (int kc2 = 0; kc2 < 2; ++kc2) {
      const f16x8 pf = kc2 ? pf1 : pf0;
      const int ch = 2 * kc2 + lh;
      #pragma unroll
      for (int db = 0; db < 2; ++db) {
        const f16x8 vf = *(const f16x8*)&Vs[ch * 512 + (db * 32 + lq) * 8];
        po[db] = __builtin_amdgcn_mfma_f32_32x32x16_f16(vf, pf, po[db], 0, 0, 0);
      }
    }
    __builtin_amdgcn_s_setprio(0);
  }
  // --- half 1 (keys 32..63) ---
  if (!TAIL) {
    float e[16];
    #pragma unroll
    for (int r = 0; r < 16; ++r) {
      e[r] = __builtin_amdgcn_exp2f(sv1[r] - mrow);
      rs += e[r];
    }
    f16x8 pf0 = pfrag(pk2(e[0], e[1]),  pk2(e[2], e[3]),
                      pk2(e[4], e[5]),  pk2(e[6], e[7]));
    f16x8 pf1 = pfrag(pk2(e[8], e[9]),  pk2(e[10], e[11]),
                      pk2(e[12], e[13]), pk2(e[14], e[15]));
    __builtin_amdgcn_s_setprio(1);
    #pragma unroll
    for (int kc2 = 0; kc2 < 2; ++kc2) {
      const f16x8 pf = kc2 ? pf1 : pf0;
      const int ch = 2 * kc2 + lh;
      #pragma unroll
      for (int db = 0; db < 2; ++db) {
        const f16x8 vf = *(const f16x8*)&Vs[(4 + ch) * 512 + (db * 32 + lq) * 8];
        po[db] = __builtin_amdgcn_mfma_f32_32x32x16_f16(vf, pf, po[db], 0, 0, 0);
      }
    }
    __builtin_amdgcn_s_setprio(0);
  }
  rs += __shfl_xor(rs, 32);
  lrow += rs;
}

__global__ __launch_bounds__(256, 4) void attn_mfma_kernel(
    const _Float16* __restrict__ Qh, const _Float16* __restrict__ Kh,
    const _Float16* __restrict__ Vt, float* __restrict__ Og)
{
  __shared__ __align__(16) union {
    struct {
      _Float16 K[2][8 * 512];   // dbuf, slabs [ch][key][8]   16 KB
      _Float16 V[2][8 * 512];   // dbuf, slabs [kch][d][8]    16 KB
    } m;                        // 32768 B
    float ot[4][32 * 68];       // epilogue staging (34816 B)
  } sm;

  const int tid = threadIdx.x;
  const int lane = tid & 63;
  const int wv = tid >> 6;
  // XCD-aware decode: 1280 blocks; all 5 q-tiles of a (b,h) share an XCD.
  const int id = blockIdx.x;
  const int idx = id >> 3;
  const int bh = (id & 7) * 32 + idx / 5;
  const int qt = idx - (idx / 5) * 5;
  const size_t base  = (size_t)bh * S * HD;
  const size_t vbase = (size_t)bh * HD * S;
  const int lq = lane & 31;   // q-col / key-row / d-row
  const int lh = lane >> 5;   // k-half selector

  // Q B-fragments: qf[kc][j] = Q[qrow][kc*16 + lh*8 + j]
  const int qrow_l = qt * 128 + wv * 32 + lq;
  const int qrow = (qrow_l < S) ? qrow_l : (S - 1);
  f16x8 qf[4];
  #pragma unroll
  for (int kc = 0; kc < 4; ++kc)
    qf[kc] = *(const f16x8*)&Qh[base + (size_t)qrow * HD + kc * 16 + lh * 8];

  f32x16 po[2] = {ZERO16, ZERO16};
  float mrow = -1e30f, lrow = 0.f;

  // Slab gload staging: wave wv fills K-slabs {wv, wv+4} (lane <-> key) and
  // V-slabs {wv, wv+4} (lane <-> d). Sources advance per tile.
  const _Float16* kg = Kh + base + (size_t)lane * HD + wv * 8;    // +32 for wv+4
  const _Float16* vg = Vt + vbase + (size_t)lane * S + wv * 8;    // +32 for wv+4

  auto gload_tile = [&](int kt, int b) {
    const _Float16* kp = kg + (size_t)kt * 64 * HD;
    const _Float16* vp = vg + kt * 64;
    gload16(kp,      &sm.m.K[b][wv * 512]);
    gload16(kp + 32, &sm.m.K[b][(wv + 4) * 512]);
    gload16(vp,      &sm.m.V[b][wv * 512]);
    gload16(vp + 32, &sm.m.V[b][(wv + 4) * 512]);
  };

  gload_tile(0, 0);
  #pragma unroll 2
  for (int kt = 0; kt < 9; ++kt) {
    const int b = kt & 1;
    __syncthreads();              // drains tile-kt gloads; orders buf^1 WAR
    gload_tile(kt + 1, b ^ 1);    // streams during attn_step below
    attn_step32<false>(&sm.m.K[b][0], &sm.m.V[b][0],
                       qf, po, mrow, lrow, lq, lh);
  }
  __syncthreads();                // tile-9 gloads drained (buf 1)
  // zero V slab 3 of buf 1 (keys 600..607 garbage; NaN * P=0 = NaN).
  // Slabs 4..7 are never read in the tail step.
  if (tid < 64)
    *(f16x8*)&sm.m.V[1][3 * 512 + tid * 8] = (f16x8){0,0,0,0,0,0,0,0};
  __syncthreads();                // zeros visible to all waves
  attn_step32<true>(&sm.m.K[1][0], &sm.m.V[1][0],
                    qf, po, mrow, lrow, lq, lh);
  __syncthreads();   // main-loop LDS fully consumed before epilogue reuse

  // epilogue: po -> per-wave ot[32 q][64 d] (stride 68) -> coalesced write
  const float invl = 1.0f / lrow;
  float* otw = &sm.ot[wv][0];
  #pragma unroll
  for (int db = 0; db < 2; ++db)
    #pragma unroll
    for (int g = 0; g < 4; ++g) {
      float4 v;
      v.x = po[db][4*g]   * invl;
      v.y = po[db][4*g+1] * invl;
      v.z = po[db][4*g+2] * invl;
      v.w = po[db][4*g+3] * invl;
      *(float4*)&otw[lq * 68 + db * 32 + g * 8 + lh * 4] = v;
    }
  __builtin_amdgcn_wave_barrier();   // ot writes before ot reads (same wave)
  {
    const int r = lane >> 1, half = lane & 1;
    const int gq = qt * 128 + wv * 32 + r;
    if (gq < S) {
      #pragma unroll
      for (int k2 = 0; k2 < 8; ++k2) {
        const float4 v = *(float4*)&otw[r * 68 + half * 32 + k2 * 4];
        *(float4*)&Og[base + (size_t)gq * HD + half * 32 + k2 * 4] = v;
      }
    }
  }
}

// ---------------------------------------------------------------------------
// Kernel C: output TCL — wave-per-token, barrier-free (unchanged).
// ---------------------------------------------------------------------------
__global__ __launch_bounds__(256) void tcl_out_kernel(
    const float* __restrict__ Og,
    const float* __restrict__ ow0, const float* __restrict__ ow1,
    const float* __restrict__ ow2, const float* __restrict__ ob,
    float* __restrict__ out)
{
  __shared__ __align__(16) float t1s[4][64 * LDT];
  __shared__ __align__(16) float t2s[4][64 * LDT];

  const int tid = threadIdx.x;
  const int wv = tid >> 6, lane = tid & 63;
  const int tok = blockIdx.x * 4 + wv;
  const int b = tok / S, t = tok - b * S;
  const int q = lane >> 3, zp = lane & 7;
  float* __restrict__ t1 = t1s[wv];
  float* __restrict__ t2 = t2s[wv];

  float2 xc[8];
  {
    const int h2g = q & 1, yg = q >> 1;
    const int h3g = 2 * (zp & 1), zg = zp >> 1;
    #pragma unroll
    for (int xx = 0; xx < 8; ++xx) {
      const int headb = (xx & 1) * 8 + h2g * 4 + h3g;
      const size_t off = ((size_t)((b * NH + headb) * S + t)) * HD
                       + (xx >> 1) * 16 + yg * 4 + zg;
      xc[xx].x = Og[off];
      xc[xx].y = Og[off + (size_t)S * HD];
    }
  }

  #pragma unroll
  for (int a = 0; a < 8; ++a) {
    float2 r = make_float2(0.f, 0.f);
    #pragma unroll
    for (int xx = 0; xx < 8; ++xx) {
      const float w = ow0[a * 8 + xx];
      r.x = fmaf(w, xc[xx].x, r.x);
      r.y = fmaf(w, xc[xx].y, r.y);
    }
    *(float2*)&t1[(a * 8 + q) * LDT + zp * 2] = r;
  }
  __builtin_amdgcn_wave_barrier();

  float2 t1r[8];
  #pragma unroll
  for (int y = 0; y < 8; ++y)
    t1r[y] = *(float2*)&t1[(q * 8 + y) * LDT + zp * 2];
  #pragma unroll
  for (int c = 0; c < 8; ++c) {
    float2 r = make_float2(0.f, 0.f);
    #pragma unroll
    for (int y = 0; y < 8; ++y) {
      const float w = ow1[c * 8 + y];
      r.x = fmaf(w, t1r[y].x, r.x);
      r.y = fmaf(w, t1r[y].y, r.y);
    }
    *(float2*)&t2[(q * 8 + c) * LDT + zp * 2] = r;
  }
  __builtin_amdgcn_wave_barrier();

  float t2r[16];
  #pragma unroll
  for (int k = 0; k < 4; ++k)
    *(float4*)&t2r[k * 4] = *(float4*)&t2[lane * LDT + k * 4];
  float bias[16];
  #pragma unroll
  for (int k = 0; k < 4; ++k)
    *(float4*)&bias[k * 4] = *(const float4*)&ob[lane * 16 + k * 4];
  float o[16];
  #pragma unroll
  for (int d = 0; d < 16; ++d) {
    float acc = 0.f;
    #pragma unroll
    for (int j = 0; j < 16; ++j)
      acc = fmaf(ow2[d * 16 + j], t2r[j], acc);
    o[d] = acc + bias[d];
  }
  #pragma unroll
  for (int k = 0; k < 4; ++k) {
    const float4 res = make_float4(o[4 * k], o[4 * k + 1],
                                   o[4 * k + 2], o[4 * k + 3]);
    *(float4*)&out[(size_t)tok * 1024 + lane * 16 + k * 4] = res;
  }
}

// ---------------------------------------------------------------------------
extern "C" void kernel_launch(void* const* d_in, const int* in_sizes, int n_in,
                              void* d_out, int out_size, void* d_ws, size_t ws_size,
                              hipStream_t stream) {
  const float* x   = (const float*)d_in[0];
  const float* qw0 = (const float*)d_in[1];
  const float* qw1 = (const float*)d_in[2];
  const float* qw2 = (const float*)d_in[3];
  const float* qb  = (const float*)d_in[4];
  const float* kw0 = (const float*)d_in[5];
  const float* kw1 = (const float*)d_in[6];
  const float* kw2 = (const float*)d_in[7];
  const float* kb  = (const float*)d_in[8];
  const float* vw0 = (const float*)d_in[9];
  const float* vw1 = (const float*)d_in[10];
  const float* vw2 = (const float*)d_in[11];
  const float* vb  = (const float*)d_in[12];
  const float* ow0 = (const float*)d_in[13];
  const float* ow1 = (const float*)d_in[14];
  const float* ow2 = (const float*)d_in[15];
  const float* ob  = (const float*)d_in[16];

  const size_t N = (size_t)NB * NH * S * HD;  // 9,830,400 elems per logical buffer
  _Float16* Qh  = (_Float16*)d_ws;
  _Float16* Kh  = Qh + N;
  _Float16* Vth = Kh + N;
  _Float16* Vh  = Vth + N;            // row-major V temp, later reused as O
  float*    O   = (float*)Vh;
  // total ws use: 3*N*2 + N*4 = 98.3 MB

  tcl_qkv_kernel<<<dim3(NB * S / 4), 256, 0, stream>>>(
      x, qw0, qw1, qw2, qb, kw0, kw1, kw2, kb, vw0, vw1, vw2, vb, Qh, Kh, Vh);
  vtrans_kernel<<<dim3(10, NH, NB), 256, 0, stream>>>(Vh, Vth);
  attn_mfma_kernel<<<dim3(1280), 256, 0, stream>>>(Qh, Kh, Vth, O);
  tcl_out_kernel<<<dim3(NB * S / 4), 256, 0, stream>>>(O, ow0, ow1, ow2, ob,
                                                       (float*)d_out);
}